// Round 3
// baseline (319.923 us; speedup 1.0000x reference)
//
#include <hip/hip_runtime.h>

// SSIM3D, (4,1,128,128,128) fp32, separable 11-tap Gaussian, scalar mean out.
//
// 3 dispatches:
//  A: x-conv + y-conv fused (sliding-window accs over y), 5 fields -> ws
//  B: z-conv + SSIM map + block reduction (sliding-window accs over z),
//     batches processed in reverse order for L3 reuse of A's freshest output
//  C: final reduce of 4096 partials
//
// This round: 1 point/thread (55 accs), 4096 waves (4/SIMD) for latency
// hiding; round 2 ran 2 waves/SIMD and sat at 34% HBM / 17% VALU.

#define DD 128
#define SLICE (128*128)        // 16384
#define S  (DD*SLICE)          // 2097152 per field per batch
#define NBATCH 4
#define C1_ 0.0001f
#define C2_ 0.0009f

__device__ __forceinline__ void make_g(float* g) {
    float s = 0.f;
#pragma unroll
    for (int i = 0; i < 11; ++i) {
        float d = (float)(i - 5);
        g[i] = __expf(-d * d / 4.5f);
        s += g[i];
    }
    float inv = 1.f / s;
#pragma unroll
    for (int i = 0; i < 11; ++i) g[i] *= inv;
}

// ---------------- Kernel A: x-conv + y-conv, walk y ----------------
// grid: 4n * 128z * 4yc * 2xh = 4096 blocks of 64 threads (1 wave).
// thread owns x = xh*64 + lane; walks 32 y outputs (42 steps).
// LDS: 11 staged rows * 2 imgs * 80 floats (74 used: x0-5 .. x0+68).
__global__ __launch_bounds__(64, 4)
void ssimA(const float* __restrict__ img1, const float* __restrict__ img2,
           float* __restrict__ fields) {
    __shared__ float rows[11][2][80];
    float g[11]; make_g(g);
    const int lane = threadIdx.x;
    const int b = blockIdx.x;
    const int xh = b & 1, yc = (b >> 1) & 3, z = (b >> 3) & 127, n = b >> 10;
    const int y0 = yc * 32;
    const int x0 = xh * 64;
    const int gx1 = x0 - 5 + lane;           // staged pos s = lane
    const int gx2 = gx1 + 64;                // staged pos s = lane+64 (lane<10)
    const bool ok1 = (gx1 >= 0) && (gx1 < 128);
    const bool ok2 = (lane < 10) && (gx2 < 128);
    const float* p1 = img1 + (size_t)n * S + (size_t)z * SLICE;
    const float* p2 = img2 + (size_t)n * S + (size_t)z * SLICE;
    float* fb = fields + (size_t)n * 5 * S + (size_t)z * SLICE + x0 + lane;

    float acc[5][11];
#pragma unroll
    for (int f = 0; f < 5; ++f)
#pragma unroll
        for (int s2 = 0; s2 < 11; ++s2) acc[f][s2] = 0.f;

#pragma unroll 1
    for (int blk = 0; blk < 4; ++blk) {
        // ---- load phase: 11 rows, clamped y, zero-padded x
#pragma unroll
        for (int t = 0; t < 11; ++t) {
            int step = blk * 11 + t;
            int y_in = y0 + step - 5;
            int ycl = min(max(y_in, 0), 127);
            size_t ro = (size_t)ycl * 128;
            rows[t][0][lane] = ok1 ? p1[ro + gx1] : 0.f;
            rows[t][1][lane] = ok1 ? p2[ro + gx1] : 0.f;
            if (lane < 10) {
                rows[t][0][lane + 64] = ok2 ? p1[ro + gx2] : 0.f;
                rows[t][1][lane + 64] = ok2 ? p2[ro + gx2] : 0.f;
            }
        }
        // ---- compute phase
#pragma unroll
        for (int t = 0; t < 11; ++t) {
            int step = blk * 11 + t;
            if (step >= 42) continue;           // uniform (last blk only)
            int y_in = y0 + step - 5;
            bool row_ok = (y_in >= 0) && (y_in < 128);

            // x-conv of the 5 fields at this thread's x
            float u1 = 0, u2 = 0, a11 = 0, a22 = 0, a12 = 0;
#pragma unroll
            for (int k = 0; k < 11; ++k) {
                float a_ = rows[t][0][lane + k];
                float b_ = rows[t][1][lane + k];
                float w = g[k];
                float ta = w * a_, tb = w * b_;
                u1 += ta; u2 += tb;
                a11 = fmaf(ta, a_, a11);
                a12 = fmaf(ta, b_, a12);
                a22 = fmaf(tb, b_, a22);
            }
            // y-accumulate: slot (t+j+1)%11 is static under the unroll
#pragma unroll
            for (int j = 0; j < 11; ++j) {
                int oo = step - 10 + j;
                float w = (row_ok && oo >= 0 && oo < 32) ? g[10 - j] : 0.f;
                const int sl = (t + j + 1) % 11;
                acc[0][sl] = fmaf(w, u1,  acc[0][sl]);
                acc[1][sl] = fmaf(w, u2,  acc[1][sl]);
                acc[2][sl] = fmaf(w, a11, acc[2][sl]);
                acc[3][sl] = fmaf(w, a22, acc[3][sl]);
                acc[4][sl] = fmaf(w, a12, acc[4][sl]);
            }
            // emit output y_out = y0 + step - 10
            if (step >= 10) {
                const int es = (t + 1) % 11;    // static
                size_t ro = (size_t)(y0 + step - 10) * 128;
#pragma unroll
                for (int f = 0; f < 5; ++f) {
                    fb[(size_t)f * S + ro] = acc[f][es];
                    acc[f][es] = 0.f;
                }
            }
        }
    }
}

// ---------------- Kernel B: z-conv + map + reduce, walk z ----------------
// grid: 4n * 128y * 4zc * 2xh = 4096 blocks of 64 threads.
// Batches processed in REVERSE (freshest A output first -> L3 hits).
__global__ __launch_bounds__(64, 4)
void ssimB(const float* __restrict__ fields, float* __restrict__ partials) {
    float g[11]; make_g(g);
    const int lane = threadIdx.x;
    const int b = blockIdx.x;
    const int xh = b & 1, zc = (b >> 1) & 3, y = (b >> 3) & 127;
    const int n = 3 - (b >> 10);
    const int z0 = zc * 32;
    const int x = xh * 64 + lane;
    const float* P0 = fields + ((size_t)(n * 5 + 0)) * S + (size_t)y * 128 + x;
    const float* P1 = fields + ((size_t)(n * 5 + 1)) * S + (size_t)y * 128 + x;
    const float* P2 = fields + ((size_t)(n * 5 + 2)) * S + (size_t)y * 128 + x;
    const float* P3 = fields + ((size_t)(n * 5 + 3)) * S + (size_t)y * 128 + x;
    const float* P4 = fields + ((size_t)(n * 5 + 4)) * S + (size_t)y * 128 + x;

    float acc[5][11];
#pragma unroll
    for (int f = 0; f < 5; ++f)
#pragma unroll
        for (int s2 = 0; s2 < 11; ++s2) acc[f][s2] = 0.f;

    float sum = 0.f;

#pragma unroll 1
    for (int blk = 0; blk < 4; ++blk) {
#pragma unroll
        for (int t = 0; t < 11; ++t) {
            int step = blk * 11 + t;
            int z_in = z0 + step - 5;
            int zcl = min(max(z_in, 0), 127);
            bool row_ok = (z_in >= 0) && (z_in < 128);
            size_t off = (size_t)zcl * SLICE;
            float f0 = P0[off];
            float f1 = P1[off];
            float f2 = P2[off];
            float f3 = P3[off];
            float f4 = P4[off];
            if (step >= 42) continue;           // uniform
#pragma unroll
            for (int j = 0; j < 11; ++j) {
                int oo = step - 10 + j;
                float w = (row_ok && oo >= 0 && oo < 32) ? g[10 - j] : 0.f;
                const int sl = (t + j + 1) % 11;
                acc[0][sl] = fmaf(w, f0, acc[0][sl]);
                acc[1][sl] = fmaf(w, f1, acc[1][sl]);
                acc[2][sl] = fmaf(w, f2, acc[2][sl]);
                acc[3][sl] = fmaf(w, f3, acc[3][sl]);
                acc[4][sl] = fmaf(w, f4, acc[4][sl]);
            }
            if (step >= 10) {
                const int es = (t + 1) % 11;    // static
                float m1 = acc[0][es], m2 = acc[1][es];
                float p11 = acc[2][es], p22 = acc[3][es];
                float p12 = acc[4][es];
                float m1s = m1 * m1, m2s = m2 * m2, m12 = m1 * m2;
                float v1 = p11 - m1s, v2 = p22 - m2s, cv = p12 - m12;
                float num = (2.f * m12 + C1_) * (2.f * cv + C2_);
                float den = (m1s + m2s + C1_) * (v1 + v2 + C2_);
                sum += num / den;
#pragma unroll
                for (int f = 0; f < 5; ++f) acc[f][es] = 0.f;
            }
        }
    }
    // wave64 reduce
#pragma unroll
    for (int o = 32; o > 0; o >>= 1) sum += __shfl_down(sum, o, 64);
    if (lane == 0) partials[blockIdx.x] = sum;
}

// ---------------- final reduce ----------------
__global__ void ssim_final(const float* __restrict__ partial, int n,
                           float* __restrict__ out, double inv_count) {
    int tid = threadIdx.x;
    double s = 0.0;
    for (int i = tid; i < n; i += 256) s += (double)partial[i];
#pragma unroll
    for (int o = 32; o > 0; o >>= 1) s += __shfl_down(s, o, 64);
    __shared__ double wsum[4];
    int lane = tid & 63, wid = tid >> 6;
    if (lane == 0) wsum[wid] = s;
    __syncthreads();
    if (tid == 0)
        out[0] = (float)((wsum[0] + wsum[1] + wsum[2] + wsum[3]) * inv_count);
}

extern "C" void kernel_launch(void* const* d_in, const int* in_sizes, int n_in,
                              void* d_out, int out_size, void* d_ws, size_t ws_size,
                              hipStream_t stream) {
    const float* img1 = (const float*)d_in[0];
    const float* img2 = (const float*)d_in[1];
    float* out = (float*)d_out;

    float* fields   = (float*)d_ws;                    // 20*S floats (167.8 MB)
    float* partials = fields + 20 * (size_t)S;         // 4096 floats

    ssimA<<<4096, 64, 0, stream>>>(img1, img2, fields);
    ssimB<<<4096, 64, 0, stream>>>(fields, partials);
    ssim_final<<<1, 256, 0, stream>>>(partials, 4096, out,
                                      1.0 / ((double)S * NBATCH));
}